// Round 7
// baseline (1386.338 us; speedup 1.0000x reference)
//
#include <hip/hip_runtime.h>
#include <hip/hip_bf16.h>

namespace {
constexpr int kD = 1024, kE = 8, kH = 4096;
constexpr int kN = 16384;     // B*T tokens
constexpr int kCap = 4096;    // N*TOP_K/E * CAPACITY_FACTOR
}

typedef __attribute__((ext_vector_type(8))) short short8;
typedef __attribute__((ext_vector_type(4))) float f32x4;

static __device__ __forceinline__ unsigned short f2bf(float f) {
    __hip_bfloat16 h = __float2bfloat16(f);   // RNE
    unsigned short s;
    __builtin_memcpy(&s, &h, 2);
    return s;
}

// async global->LDS, 16 B per lane; LDS dest is wave-uniform base + lane*16
static __device__ __forceinline__ void gload_lds16(const unsigned short* g, unsigned short* l) {
    __builtin_amdgcn_global_load_lds(
        (const __attribute__((address_space(1))) unsigned int*)g,
        (__attribute__((address_space(3))) unsigned int*)l, 16, 0, 0);
}

// ---------------- zero output ----------------
__global__ __launch_bounds__(256) void moe_zero_out(float4* __restrict__ p, int n4)
{
    int i = blockIdx.x * 256 + threadIdx.x;
    if (i < n4) p[i] = make_float4(0.f, 0.f, 0.f, 0.f);
}

// ---------------- x fp32 -> bf16 ----------------
__global__ __launch_bounds__(256) void moe_cvt_x(const float4* __restrict__ in,
                                                 short8* __restrict__ outp, int n8)
{
    int i = blockIdx.x * 256 + threadIdx.x;
    if (i >= n8) return;
    const float4 a = in[2 * i], b = in[2 * i + 1];
    short8 v;
    v[0] = (short)f2bf(a.x); v[1] = (short)f2bf(a.y);
    v[2] = (short)f2bf(a.z); v[3] = (short)f2bf(a.w);
    v[4] = (short)f2bf(b.x); v[5] = (short)f2bf(b.y);
    v[6] = (short)f2bf(b.z); v[7] = (short)f2bf(b.w);
    outp[i] = v;
}

// ---------------- transpose + convert: in[z][R][C] fp32 -> out[z][C][R] bf16 ----------------
__global__ __launch_bounds__(256) void moe_tcvt(const float* __restrict__ in,
                                                unsigned short* __restrict__ outp,
                                                int R, int C)
{
    const float* src = in + (size_t)blockIdx.z * R * C;
    unsigned short* dst = outp + (size_t)blockIdx.z * R * C;
    const int c0 = blockIdx.x * 64, r0 = blockIdx.y * 64;
    __shared__ float t[64][68];
    const int tid = (int)threadIdx.x;
    const int tr = tid >> 2;            // 0..63
    const int tc = (tid & 3) * 16;      // 0/16/32/48
    #pragma unroll
    for (int j = 0; j < 4; ++j) {
        const float4 v = *(const float4*)(src + (size_t)(r0 + tr) * C + c0 + tc + j * 4);
        *(float4*)&t[tr][tc + j * 4] = v;
    }
    __syncthreads();
    unsigned short o[16];
    #pragma unroll
    for (int j = 0; j < 16; ++j) o[j] = f2bf(t[tc + j][tr]);
    unsigned short* dp = dst + (size_t)(c0 + tr) * R + r0 + tc;
    *(short8*)dp = *(const short8*)&o[0];
    *(short8*)(dp + 8) = *(const short8*)&o[8];
}

// ---------------- router: one wave per token ----------------
__global__ __launch_bounds__(256) void moe_router(
    const float* __restrict__ x, const float* __restrict__ noise_raw,
    const float* __restrict__ Wr, const float* __restrict__ br,
    const float* __restrict__ Wn, const float* __restrict__ bn,
    int2* __restrict__ topIdx, float2* __restrict__ topProb)
{
    const int wave = threadIdx.x >> 6;
    const int lane = threadIdx.x & 63;
    const int n = blockIdx.x * 4 + wave;
    const float* xr = x + (size_t)n * kD;

    float accr[kE], accn[kE];
    #pragma unroll
    for (int e = 0; e < kE; ++e) { accr[e] = 0.f; accn[e] = 0.f; }

    #pragma unroll
    for (int c = 0; c < 4; ++c) {
        const int d0 = c * 256 + lane * 4;
        const float4 xv = *(const float4*)(xr + d0);
        const float xs[4] = {xv.x, xv.y, xv.z, xv.w};
        #pragma unroll
        for (int j = 0; j < 4; ++j) {
            const float4* wr4 = (const float4*)(Wr + (size_t)(d0 + j) * kE);
            const float4* wn4 = (const float4*)(Wn + (size_t)(d0 + j) * kE);
            const float4 r0 = wr4[0], r1 = wr4[1];
            const float4 m0 = wn4[0], m1 = wn4[1];
            const float xj = xs[j];
            accr[0] += xj * r0.x; accr[1] += xj * r0.y; accr[2] += xj * r0.z; accr[3] += xj * r0.w;
            accr[4] += xj * r1.x; accr[5] += xj * r1.y; accr[6] += xj * r1.z; accr[7] += xj * r1.w;
            accn[0] += xj * m0.x; accn[1] += xj * m0.y; accn[2] += xj * m0.z; accn[3] += xj * m0.w;
            accn[4] += xj * m1.x; accn[5] += xj * m1.y; accn[6] += xj * m1.z; accn[7] += xj * m1.w;
        }
    }
    #pragma unroll
    for (int e = 0; e < kE; ++e) {
        #pragma unroll
        for (int off = 32; off >= 1; off >>= 1) {
            accr[e] += __shfl_xor(accr[e], off, 64);
            accn[e] += __shfl_xor(accn[e], off, 64);
        }
    }
    if (lane == 0) {
        float noisy[kE];
        #pragma unroll
        for (int e = 0; e < kE; ++e) {
            const float lg = accr[e] + br[e];
            const float nl = accn[e] + bn[e];
            const float sp = fmaxf(nl, 0.f) + log1pf(expf(-fabsf(nl)));
            noisy[e] = lg + noise_raw[(size_t)n * kE + e] * sp;
        }
        int i0 = 0;
        #pragma unroll
        for (int e = 1; e < kE; ++e) if (noisy[e] > noisy[i0]) i0 = e;
        int i1 = (i0 == 0) ? 1 : 0;
        #pragma unroll
        for (int e = 0; e < kE; ++e) if (e != i0 && noisy[e] > noisy[i1]) i1 = e;
        const float ex = expf(noisy[i1] - noisy[i0]);
        topIdx[n] = make_int2(i0, i1);
        topProb[n] = make_float2(1.f / (1.f + ex), ex / (1.f + ex));
    }
}

// ---------------- dispatch: stable compaction in flat token order ----------------
__global__ void moe_dispatch(
    const int2* __restrict__ topIdx, const float2* __restrict__ topProb,
    int* __restrict__ tokList, float* __restrict__ gateList, int* __restrict__ cnt)
{
    const int e = blockIdx.x;
    const int lane = threadIdx.x;   // block = 64
    const unsigned long long below = (lane == 0) ? 0ull : ((~0ull) >> (64 - lane));
    int base = 0;
    for (int it = 0; it < kN / 64; ++it) {
        const int n = it * 64 + lane;
        const int2 ti = topIdx[n];
        const float2 tp = topProb[n];
        const bool sel = (ti.x == e) || (ti.y == e);
        const float g = (ti.x == e) ? tp.x : tp.y;
        const unsigned long long m = __ballot(sel);
        if (sel) {
            const int slot = base + __popcll(m & below);
            if (slot < kCap) { tokList[e * kCap + slot] = n; gateList[e * kCap + slot] = g; }
        }
        base += __popcll(m);
    }
    if (lane == 0) cnt[e] = base < kCap ? base : kCap;
}

// L2-locality block remap: the gx n-blocks of one m-panel land on one XCD,
// temporally adjacent. Requires gridDim.y % 8 == 0.
static __device__ __forceinline__ void remap_mn(int gx, int& mblk, int& nblk)
{
    const int l = blockIdx.y * gx + blockIdx.x;
    const int xcd = l & 7;
    const int pos = l >> 3;
    nblk = pos % gx;
    mblk = xcd + 8 * (pos / gx);
}

// ================= FFN pass 1: H = relu(Xg @ W1[e] + b1[e])  =================
// 128x128 tile, BK=32; depth-3 counted-vmcnt pipeline: loads stay in flight
// across raw s_barrier (never drained to 0 in the main loop).
__global__ __launch_bounds__(256) void moe_ffn1_g(
    const unsigned short* __restrict__ xb, const unsigned short* __restrict__ W1t,
    const float* __restrict__ b1,
    const int* __restrict__ tokList, const int* __restrict__ cnt,
    unsigned short* __restrict__ Hbuf, int e_base)
{
    const int e = e_base + blockIdx.z;
    const int count = cnt[e];
    int mblk, nblk;
    remap_mn((int)gridDim.x, mblk, nblk);
    const int m0 = mblk * 128;
    if (m0 >= count) return;
    const int n0 = nblk * 128;

    __shared__ unsigned short As[3][128 * 32];
    __shared__ unsigned short Bs[3][128 * 32];

    const int tid = (int)threadIdx.x;
    const int lane = tid & 63;
    const int w = tid >> 6;

    // staging: wave w owns 1024-B chunks {2w, 2w+1}; (row, slot s) at byte
    // row*64 + (s ^ ((row>>1)&3))*16; linear dest => inverse-swizzled source col.
    const int scol = ((lane & 3) ^ ((lane >> 3) & 3)) * 8;   // ushorts
    const int c0i = 2 * w, c1i = 2 * w + 1;
    const int ra0 = 16 * c0i + (lane >> 2);
    const int ra1 = 16 * c1i + (lane >> 2);
    int am0 = m0 + ra0; if (am0 >= count) am0 = count - 1;
    int am1 = m0 + ra1; if (am1 >= count) am1 = count - 1;
    const int* tok = tokList + e * kCap;
    const unsigned short* aSrc0 = xb + (size_t)tok[am0] * kD + scol;
    const unsigned short* aSrc1 = xb + (size_t)tok[am1] * kD + scol;
    const unsigned short* We = W1t + (size_t)e * kD * kH;              // [kH][kD]
    const unsigned short* bSrc0 = We + (size_t)(n0 + ra0) * kD + scol;
    const unsigned short* bSrc1 = We + (size_t)(n0 + ra1) * kD + scol;

    const int l15 = lane & 15, g = lane >> 4;
    const int wrow = (w >> 1) * 64, wcol = (w & 1) * 64;
    const int fragOff = l15 * 64 + ((g ^ ((l15 >> 1) & 3)) * 16);   // bytes

    f32x4 acc[4][4] = {};

    auto stage = [&](int t, int buf) {
        const int kn = t * 32;
        gload_lds16(aSrc0 + kn, &As[buf][c0i * 512]);
        gload_lds16(aSrc1 + kn, &As[buf][c1i * 512]);
        gload_lds16(bSrc0 + kn, &Bs[buf][c0i * 512]);
        gload_lds16(bSrc1 + kn, &Bs[buf][c1i * 512]);
    };

    constexpr int nt = kD / 32;
    stage(0, 0);
    stage(1, 1);

    for (int t = 0; t < nt; ++t) {
        // WAR: own frag ds_reads (iter t-1) retired before signaling
        asm volatile("s_waitcnt lgkmcnt(0)" ::: "memory");
        // RAW: own tile-t loads done; tile t+1's stay in flight across barrier
        if (t + 1 < nt) asm volatile("s_waitcnt vmcnt(4)" ::: "memory");
        else            asm volatile("s_waitcnt vmcnt(0)" ::: "memory");
        __builtin_amdgcn_s_barrier();      // all waves' tile-t loads landed
        __builtin_amdgcn_sched_barrier(0);
        if (t + 2 < nt) stage(t + 2, (t + 2) % 3);   // overwrites buf of t-1: safe after barrier

        const char* Ab = (const char*)As[t % 3];
        const char* Bb = (const char*)Bs[t % 3];
        short8 af[4], bfr[4];
        #pragma unroll
        for (int mm = 0; mm < 4; ++mm)
            af[mm] = *(const short8*)(Ab + (wrow + mm * 16) * 64 + fragOff);
        #pragma unroll
        for (int nn = 0; nn < 4; ++nn)
            bfr[nn] = *(const short8*)(Bb + (wcol + nn * 16) * 64 + fragOff);
        #pragma unroll
        for (int mm = 0; mm < 4; ++mm)
            #pragma unroll
            for (int nn = 0; nn < 4; ++nn)
                acc[mm][nn] = __builtin_amdgcn_mfma_f32_16x16x32_bf16(
                    af[mm], bfr[nn], acc[mm][nn], 0, 0, 0);
    }

    const float* be = b1 + (size_t)e * kH + n0;
    unsigned short* H = Hbuf + (size_t)blockIdx.z * kCap * kH;
    #pragma unroll
    for (int mm = 0; mm < 4; ++mm) {
        #pragma unroll
        for (int i = 0; i < 4; ++i) {
            const int r = m0 + wrow + mm * 16 + g * 4 + i;
            if (r >= count) continue;
            unsigned short* hrow = H + (size_t)r * kH + n0;
            #pragma unroll
            for (int nn = 0; nn < 4; ++nn) {
                const int c = wcol + nn * 16 + l15;
                hrow[c] = f2bf(fmaxf(acc[mm][nn][i] + be[c], 0.f));
            }
        }
    }
}

// ================= FFN pass 2 + combine: out[tok] += gate*(H @ W2[e] + b2[e]) =================
__global__ __launch_bounds__(256) void moe_ffn2_g(
    const unsigned short* __restrict__ Hbuf, const unsigned short* __restrict__ W2t,
    const float* __restrict__ b2,
    const int* __restrict__ tokList, const float* __restrict__ gateList,
    const int* __restrict__ cnt, float* __restrict__ out, int e_base)
{
    const int e = e_base + blockIdx.z;
    const int count = cnt[e];
    int mblk, nblk;
    remap_mn((int)gridDim.x, mblk, nblk);
    const int m0 = mblk * 128;
    if (m0 >= count) return;
    const int n0 = nblk * 128;

    __shared__ unsigned short As[3][128 * 32];
    __shared__ unsigned short Bs[3][128 * 32];

    const int tid = (int)threadIdx.x;
    const int lane = tid & 63;
    const int w = tid >> 6;

    const int scol = ((lane & 3) ^ ((lane >> 3) & 3)) * 8;
    const int c0i = 2 * w, c1i = 2 * w + 1;
    const int ra0 = 16 * c0i + (lane >> 2);
    const int ra1 = 16 * c1i + (lane >> 2);
    const unsigned short* H = Hbuf + (size_t)blockIdx.z * kCap * kH;
    const unsigned short* aSrc0 = H + (size_t)(m0 + ra0) * kH + scol;  // junk rows masked in epilogue
    const unsigned short* aSrc1 = H + (size_t)(m0 + ra1) * kH + scol;
    const unsigned short* We = W2t + (size_t)e * kH * kD;              // [kD][kH]
    const unsigned short* bSrc0 = We + (size_t)(n0 + ra0) * kH + scol;
    const unsigned short* bSrc1 = We + (size_t)(n0 + ra1) * kH + scol;

    const int l15 = lane & 15, g = lane >> 4;
    const int wrow = (w >> 1) * 64, wcol = (w & 1) * 64;
    const int fragOff = l15 * 64 + ((g ^ ((l15 >> 1) & 3)) * 16);

    f32x4 acc[4][4] = {};

    auto stage = [&](int t, int buf) {
        const int kn = t * 32;
        gload_lds16(aSrc0 + kn, &As[buf][c0i * 512]);
        gload_lds16(aSrc1 + kn, &As[buf][c1i * 512]);
        gload_lds16(bSrc0 + kn, &Bs[buf][c0i * 512]);
        gload_lds16(bSrc1 + kn, &Bs[buf][c1i * 512]);
    };

    constexpr int nt = kH / 32;
    stage(0, 0);
    stage(1, 1);

    for (int t = 0; t < nt; ++t) {
        asm volatile("s_waitcnt lgkmcnt(0)" ::: "memory");
        if (t + 1 < nt) asm volatile("s_waitcnt vmcnt(4)" ::: "memory");
        else            asm volatile("s_waitcnt vmcnt(0)" ::: "memory");
        __builtin_amdgcn_s_barrier();
        __builtin_amdgcn_sched_barrier(0);
        if (t + 2 < nt) stage(t + 2, (t + 2) % 3);

        const char* Ab = (const char*)As[t % 3];
        const char* Bb = (const char*)Bs[t % 3];
        short8 af[4], bfr[4];
        #pragma unroll
        for (int mm = 0; mm < 4; ++mm)
            af[mm] = *(const short8*)(Ab + (wrow + mm * 16) * 64 + fragOff);
        #pragma unroll
        for (int nn = 0; nn < 4; ++nn)
            bfr[nn] = *(const short8*)(Bb + (wcol + nn * 16) * 64 + fragOff);
        #pragma unroll
        for (int mm = 0; mm < 4; ++mm)
            #pragma unroll
            for (int nn = 0; nn < 4; ++nn)
                acc[mm][nn] = __builtin_amdgcn_mfma_f32_16x16x32_bf16(
                    af[mm], bfr[nn], acc[mm][nn], 0, 0, 0);
    }

    const float* be = b2 + (size_t)e * kD + n0;
    const int* tok = tokList + e * kCap;
    const float* gate = gateList + e * kCap;
    #pragma unroll
    for (int mm = 0; mm < 4; ++mm) {
        #pragma unroll
        for (int i = 0; i < 4; ++i) {
            const int r = m0 + wrow + mm * 16 + g * 4 + i;
            if (r >= count) continue;
            const int tokn = tok[r];
            const float gr = gate[r];
            float* orow = out + (size_t)tokn * kD + n0;
            #pragma unroll
            for (int nn = 0; nn < 4; ++nn) {
                const int c = wcol + nn * 16 + l15;
                atomicAdd(orow + c, (acc[mm][nn][i] + be[c]) * gr);   // <=2 addends: deterministic
            }
        }
    }
}

// ---------------- launch ----------------
extern "C" void kernel_launch(void* const* d_in, const int* in_sizes, int n_in,
                              void* d_out, int out_size, void* d_ws, size_t ws_size,
                              hipStream_t stream)
{
    const float* x         = (const float*)d_in[0];
    const float* noise_raw = (const float*)d_in[1];
    const float* Wr        = (const float*)d_in[2];
    const float* br        = (const float*)d_in[3];
    const float* Wn        = (const float*)d_in[4];
    const float* bn        = (const float*)d_in[5];
    const float* W1        = (const float*)d_in[6];
    const float* b1        = (const float*)d_in[7];
    const float* W2        = (const float*)d_in[8];
    const float* b2        = (const float*)d_in[9];
    float* out = (float*)d_out;

    char* ws = (char*)d_ws;
    size_t off = 0;
    auto alloc = [&](size_t bytes) -> void* {
        void* p = ws + off;
        off = (off + bytes + 255) & ~(size_t)255;
        return p;
    };
    int2*   topIdx   = (int2*)  alloc((size_t)kN * sizeof(int2));
    float2* topProb  = (float2*)alloc((size_t)kN * sizeof(float2));
    int*    tokList  = (int*)   alloc((size_t)kE * kCap * sizeof(int));
    float*  gateList = (float*) alloc((size_t)kE * kCap * sizeof(float));
    int*    cnt      = (int*)   alloc((size_t)kE * sizeof(int));

    unsigned short* xb  = (unsigned short*)alloc((size_t)kN * kD * 2);        // 32 MB
    unsigned short* W1t = (unsigned short*)alloc((size_t)kE * kD * kH * 2);   // 64 MB
    unsigned short* W2t = (unsigned short*)alloc((size_t)kE * kH * kD * 2);   // 64 MB

    const size_t HB = (size_t)kCap * kH * 2;   // 32 MB / expert
    size_t rem = (ws_size > off) ? ws_size - off : 0;
    int G = (int)(rem / HB);
    if (G > 4) G = 4;   // 289 MB total known to fit (round 2 ran G=8 at 289 MB)
    if (G < 1) G = 1;
    unsigned short* Hbuf = (unsigned short*)(ws + off);

    moe_zero_out<<<(kN * kD / 4 + 255) / 256, 256, 0, stream>>>((float4*)out, kN * kD / 4);
    moe_router<<<kN / 4, 256, 0, stream>>>(x, noise_raw, Wr, br, Wn, bn, topIdx, topProb);
    moe_dispatch<<<kE, 64, 0, stream>>>(topIdx, topProb, tokList, gateList, cnt);
    moe_cvt_x<<<kN * kD / 8 / 256, 256, 0, stream>>>((const float4*)x, (short8*)xb, kN * kD / 8);
    // W1 [E][D][H] -> W1t [E][H][D]
    moe_tcvt<<<dim3(kH / 64, kD / 64, kE), 256, 0, stream>>>(W1, W1t, kD, kH);
    // W2 [E][H][D] -> W2t [E][D][H]
    moe_tcvt<<<dim3(kD / 64, kH / 64, kE), 256, 0, stream>>>(W2, W2t, kH, kD);

    for (int e0 = 0; e0 < kE; e0 += G) {
        const int gz = (kE - e0 < G) ? (kE - e0) : G;
        moe_ffn1_g<<<dim3(kH / 128, kCap / 128, gz), 256, 0, stream>>>(
            xb, W1t, b1, tokList, cnt, Hbuf, e0);
        moe_ffn2_g<<<dim3(kD / 128, kCap / 128, gz), 256, 0, stream>>>(
            Hbuf, W2t, b2, tokList, gateList, cnt, out, e0);
    }
}

// Round 8
// 1259.059 us; speedup vs baseline: 1.1011x; 1.1011x over previous
//
#include <hip/hip_runtime.h>
#include <hip/hip_bf16.h>

namespace {
constexpr int kD = 1024, kE = 8, kH = 4096;
constexpr int kN = 16384;     // B*T tokens
constexpr int kCap = 4096;    // N*TOP_K/E * CAPACITY_FACTOR
}

typedef __attribute__((ext_vector_type(8))) short short8;
typedef __attribute__((ext_vector_type(4))) float f32x4;

static __device__ __forceinline__ unsigned short f2bf(float f) {
    __hip_bfloat16 h = __float2bfloat16(f);   // RNE
    unsigned short s;
    __builtin_memcpy(&s, &h, 2);
    return s;
}

// async global->LDS, 16 B per lane; LDS dest is wave-uniform base + lane*16
static __device__ __forceinline__ void gload_lds16(const unsigned short* g, unsigned short* l) {
    __builtin_amdgcn_global_load_lds(
        (const __attribute__((address_space(1))) unsigned int*)g,
        (__attribute__((address_space(3))) unsigned int*)l, 16, 0, 0);
}

// ---------------- zero output ----------------
__global__ __launch_bounds__(256) void moe_zero_out(float4* __restrict__ p, int n4)
{
    int i = blockIdx.x * 256 + threadIdx.x;
    if (i < n4) p[i] = make_float4(0.f, 0.f, 0.f, 0.f);
}

// ---------------- x fp32 -> bf16 ----------------
__global__ __launch_bounds__(256) void moe_cvt_x(const float4* __restrict__ in,
                                                 short8* __restrict__ outp, int n8)
{
    int i = blockIdx.x * 256 + threadIdx.x;
    if (i >= n8) return;
    const float4 a = in[2 * i], b = in[2 * i + 1];
    short8 v;
    v[0] = (short)f2bf(a.x); v[1] = (short)f2bf(a.y);
    v[2] = (short)f2bf(a.z); v[3] = (short)f2bf(a.w);
    v[4] = (short)f2bf(b.x); v[5] = (short)f2bf(b.y);
    v[6] = (short)f2bf(b.z); v[7] = (short)f2bf(b.w);
    outp[i] = v;
}

// ---------------- transpose + convert: in[z][R][C] fp32 -> out[z][C][R] bf16 ----------------
__global__ __launch_bounds__(256) void moe_tcvt(const float* __restrict__ in,
                                                unsigned short* __restrict__ outp,
                                                int R, int C)
{
    const float* src = in + (size_t)blockIdx.z * R * C;
    unsigned short* dst = outp + (size_t)blockIdx.z * R * C;
    const int c0 = blockIdx.x * 64, r0 = blockIdx.y * 64;
    __shared__ float t[64][68];
    const int tid = (int)threadIdx.x;
    const int tr = tid >> 2;            // 0..63
    const int tc = (tid & 3) * 16;      // 0/16/32/48
    #pragma unroll
    for (int j = 0; j < 4; ++j) {
        const float4 v = *(const float4*)(src + (size_t)(r0 + tr) * C + c0 + tc + j * 4);
        *(float4*)&t[tr][tc + j * 4] = v;
    }
    __syncthreads();
    unsigned short o[16];
    #pragma unroll
    for (int j = 0; j < 16; ++j) o[j] = f2bf(t[tc + j][tr]);
    unsigned short* dp = dst + (size_t)(c0 + tr) * R + r0 + tc;
    *(short8*)dp = *(const short8*)&o[0];
    *(short8*)(dp + 8) = *(const short8*)&o[8];
}

// ---------------- router: one wave per token ----------------
__global__ __launch_bounds__(256) void moe_router(
    const float* __restrict__ x, const float* __restrict__ noise_raw,
    const float* __restrict__ Wr, const float* __restrict__ br,
    const float* __restrict__ Wn, const float* __restrict__ bn,
    int2* __restrict__ topIdx, float2* __restrict__ topProb)
{
    const int wave = threadIdx.x >> 6;
    const int lane = threadIdx.x & 63;
    const int n = blockIdx.x * 4 + wave;
    const float* xr = x + (size_t)n * kD;

    float accr[kE], accn[kE];
    #pragma unroll
    for (int e = 0; e < kE; ++e) { accr[e] = 0.f; accn[e] = 0.f; }

    #pragma unroll
    for (int c = 0; c < 4; ++c) {
        const int d0 = c * 256 + lane * 4;
        const float4 xv = *(const float4*)(xr + d0);
        const float xs[4] = {xv.x, xv.y, xv.z, xv.w};
        #pragma unroll
        for (int j = 0; j < 4; ++j) {
            const float4* wr4 = (const float4*)(Wr + (size_t)(d0 + j) * kE);
            const float4* wn4 = (const float4*)(Wn + (size_t)(d0 + j) * kE);
            const float4 r0 = wr4[0], r1 = wr4[1];
            const float4 m0 = wn4[0], m1 = wn4[1];
            const float xj = xs[j];
            accr[0] += xj * r0.x; accr[1] += xj * r0.y; accr[2] += xj * r0.z; accr[3] += xj * r0.w;
            accr[4] += xj * r1.x; accr[5] += xj * r1.y; accr[6] += xj * r1.z; accr[7] += xj * r1.w;
            accn[0] += xj * m0.x; accn[1] += xj * m0.y; accn[2] += xj * m0.z; accn[3] += xj * m0.w;
            accn[4] += xj * m1.x; accn[5] += xj * m1.y; accn[6] += xj * m1.z; accn[7] += xj * m1.w;
        }
    }
    #pragma unroll
    for (int e = 0; e < kE; ++e) {
        #pragma unroll
        for (int off = 32; off >= 1; off >>= 1) {
            accr[e] += __shfl_xor(accr[e], off, 64);
            accn[e] += __shfl_xor(accn[e], off, 64);
        }
    }
    if (lane == 0) {
        float noisy[kE];
        #pragma unroll
        for (int e = 0; e < kE; ++e) {
            const float lg = accr[e] + br[e];
            const float nl = accn[e] + bn[e];
            const float sp = fmaxf(nl, 0.f) + log1pf(expf(-fabsf(nl)));
            noisy[e] = lg + noise_raw[(size_t)n * kE + e] * sp;
        }
        int i0 = 0;
        #pragma unroll
        for (int e = 1; e < kE; ++e) if (noisy[e] > noisy[i0]) i0 = e;
        int i1 = (i0 == 0) ? 1 : 0;
        #pragma unroll
        for (int e = 0; e < kE; ++e) if (e != i0 && noisy[e] > noisy[i1]) i1 = e;
        const float ex = expf(noisy[i1] - noisy[i0]);
        topIdx[n] = make_int2(i0, i1);
        topProb[n] = make_float2(1.f / (1.f + ex), ex / (1.f + ex));
    }
}

// ---------------- dispatch: stable compaction in flat token order ----------------
__global__ void moe_dispatch(
    const int2* __restrict__ topIdx, const float2* __restrict__ topProb,
    int* __restrict__ tokList, float* __restrict__ gateList, int* __restrict__ cnt)
{
    const int e = blockIdx.x;
    const int lane = threadIdx.x;   // block = 64
    const unsigned long long below = (lane == 0) ? 0ull : ((~0ull) >> (64 - lane));
    int base = 0;
    for (int it = 0; it < kN / 64; ++it) {
        const int n = it * 64 + lane;
        const int2 ti = topIdx[n];
        const float2 tp = topProb[n];
        const bool sel = (ti.x == e) || (ti.y == e);
        const float g = (ti.x == e) ? tp.x : tp.y;
        const unsigned long long m = __ballot(sel);
        if (sel) {
            const int slot = base + __popcll(m & below);
            if (slot < kCap) { tokList[e * kCap + slot] = n; gateList[e * kCap + slot] = g; }
        }
        base += __popcll(m);
    }
    if (lane == 0) cnt[e] = base < kCap ? base : kCap;
}

// L2-locality block remap: the gx n-blocks of one m-panel land on one XCD,
// temporally adjacent. Requires gridDim.y % 8 == 0. (Verified pass in round 7.)
static __device__ __forceinline__ void remap_mn(int gx, int& mblk, int& nblk)
{
    const int l = blockIdx.y * gx + blockIdx.x;
    const int xcd = l & 7;
    const int pos = l >> 3;
    nblk = pos % gx;
    mblk = xcd + 8 * (pos / gx);
}

// ================= FFN pass 1: H = relu(Xg @ W1[e] + b1[e])  =================
// 128x128 tile, BK=32, 2-phase prefetch: double-buffered LDS, stage(t+1) issued
// before compute(t), ONE __syncthreads per K-step (drains exactly tile t+1's loads).
__global__ __launch_bounds__(256) void moe_ffn1_g(
    const unsigned short* __restrict__ xb, const unsigned short* __restrict__ W1t,
    const float* __restrict__ b1,
    const int* __restrict__ tokList, const int* __restrict__ cnt,
    unsigned short* __restrict__ Hbuf, int e_base)
{
    const int e = e_base + blockIdx.z;
    const int count = cnt[e];
    int mblk, nblk;
    remap_mn((int)gridDim.x, mblk, nblk);
    const int m0 = mblk * 128;
    if (m0 >= count) return;
    const int n0 = nblk * 128;

    __shared__ unsigned short As[2][128 * 32];
    __shared__ unsigned short Bs[2][128 * 32];

    const int tid = (int)threadIdx.x;
    const int lane = tid & 63;
    const int w = tid >> 6;

    // staging: wave w owns 1024-B chunks {2w, 2w+1}; (row, slot s) at byte
    // row*64 + (s ^ ((row>>1)&3))*16; linear dest => inverse-swizzled source col.
    const int scol = ((lane & 3) ^ ((lane >> 3) & 3)) * 8;   // ushorts
    const int c0i = 2 * w, c1i = 2 * w + 1;
    const int ra0 = 16 * c0i + (lane >> 2);
    const int ra1 = 16 * c1i + (lane >> 2);
    int am0 = m0 + ra0; if (am0 >= count) am0 = count - 1;
    int am1 = m0 + ra1; if (am1 >= count) am1 = count - 1;
    const int* tok = tokList + e * kCap;
    const unsigned short* aSrc0 = xb + (size_t)tok[am0] * kD + scol;
    const unsigned short* aSrc1 = xb + (size_t)tok[am1] * kD + scol;
    const unsigned short* We = W1t + (size_t)e * kD * kH;              // [kH][kD]
    const unsigned short* bSrc0 = We + (size_t)(n0 + ra0) * kD + scol;
    const unsigned short* bSrc1 = We + (size_t)(n0 + ra1) * kD + scol;

    const int l15 = lane & 15, g = lane >> 4;
    const int wrow = (w >> 1) * 64, wcol = (w & 1) * 64;
    const int fragOff = l15 * 64 + ((g ^ ((l15 >> 1) & 3)) * 16);   // bytes

    f32x4 acc[4][4] = {};

    // prologue: stage tile 0 into buf 0
    gload_lds16(aSrc0, &As[0][c0i * 512]);
    gload_lds16(aSrc1, &As[0][c1i * 512]);
    gload_lds16(bSrc0, &Bs[0][c0i * 512]);
    gload_lds16(bSrc1, &Bs[0][c1i * 512]);
    __syncthreads();

    constexpr int nt = kD / 32;
    for (int t = 0; t < nt; ++t) {
        const int buf = t & 1;
        if (t + 1 < nt) {            // issue next-tile loads; overlap with MFMA below
            const int kn = (t + 1) * 32;
            gload_lds16(aSrc0 + kn, &As[buf ^ 1][c0i * 512]);
            gload_lds16(aSrc1 + kn, &As[buf ^ 1][c1i * 512]);
            gload_lds16(bSrc0 + kn, &Bs[buf ^ 1][c0i * 512]);
            gload_lds16(bSrc1 + kn, &Bs[buf ^ 1][c1i * 512]);
        }
        const char* Ab = (const char*)As[buf];
        const char* Bb = (const char*)Bs[buf];
        short8 af[4], bfr[4];
        #pragma unroll
        for (int mm = 0; mm < 4; ++mm)
            af[mm] = *(const short8*)(Ab + (wrow + mm * 16) * 64 + fragOff);
        #pragma unroll
        for (int nn = 0; nn < 4; ++nn)
            bfr[nn] = *(const short8*)(Bb + (wcol + nn * 16) * 64 + fragOff);
        #pragma unroll
        for (int mm = 0; mm < 4; ++mm)
            #pragma unroll
            for (int nn = 0; nn < 4; ++nn)
                acc[mm][nn] = __builtin_amdgcn_mfma_f32_16x16x32_bf16(
                    af[mm], bfr[nn], acc[mm][nn], 0, 0, 0);
        if (t + 1 < nt) __syncthreads();   // drains vmcnt(0): next buf ready
    }

    const float* be = b1 + (size_t)e * kH + n0;
    unsigned short* H = Hbuf + (size_t)blockIdx.z * kCap * kH;
    #pragma unroll
    for (int mm = 0; mm < 4; ++mm) {
        #pragma unroll
        for (int i = 0; i < 4; ++i) {
            const int r = m0 + wrow + mm * 16 + g * 4 + i;
            if (r >= count) continue;
            unsigned short* hrow = H + (size_t)r * kH + n0;
            #pragma unroll
            for (int nn = 0; nn < 4; ++nn) {
                const int c = wcol + nn * 16 + l15;
                hrow[c] = f2bf(fmaxf(acc[mm][nn][i] + be[c], 0.f));
            }
        }
    }
}

// ================= FFN pass 2 + combine: out[tok] += gate*(H @ W2[e] + b2[e]) =================
__global__ __launch_bounds__(256) void moe_ffn2_g(
    const unsigned short* __restrict__ Hbuf, const unsigned short* __restrict__ W2t,
    const float* __restrict__ b2,
    const int* __restrict__ tokList, const float* __restrict__ gateList,
    const int* __restrict__ cnt, float* __restrict__ out, int e_base)
{
    const int e = e_base + blockIdx.z;
    const int count = cnt[e];
    int mblk, nblk;
    remap_mn((int)gridDim.x, mblk, nblk);
    const int m0 = mblk * 128;
    if (m0 >= count) return;
    const int n0 = nblk * 128;

    __shared__ unsigned short As[2][128 * 32];
    __shared__ unsigned short Bs[2][128 * 32];

    const int tid = (int)threadIdx.x;
    const int lane = tid & 63;
    const int w = tid >> 6;

    const int scol = ((lane & 3) ^ ((lane >> 3) & 3)) * 8;
    const int c0i = 2 * w, c1i = 2 * w + 1;
    const int ra0 = 16 * c0i + (lane >> 2);
    const int ra1 = 16 * c1i + (lane >> 2);
    const unsigned short* H = Hbuf + (size_t)blockIdx.z * kCap * kH;
    const unsigned short* aSrc0 = H + (size_t)(m0 + ra0) * kH + scol;  // junk rows masked in epilogue
    const unsigned short* aSrc1 = H + (size_t)(m0 + ra1) * kH + scol;
    const unsigned short* We = W2t + (size_t)e * kH * kD;              // [kD][kH]
    const unsigned short* bSrc0 = We + (size_t)(n0 + ra0) * kH + scol;
    const unsigned short* bSrc1 = We + (size_t)(n0 + ra1) * kH + scol;

    const int l15 = lane & 15, g = lane >> 4;
    const int wrow = (w >> 1) * 64, wcol = (w & 1) * 64;
    const int fragOff = l15 * 64 + ((g ^ ((l15 >> 1) & 3)) * 16);

    f32x4 acc[4][4] = {};

    gload_lds16(aSrc0, &As[0][c0i * 512]);
    gload_lds16(aSrc1, &As[0][c1i * 512]);
    gload_lds16(bSrc0, &Bs[0][c0i * 512]);
    gload_lds16(bSrc1, &Bs[0][c1i * 512]);
    __syncthreads();

    constexpr int nt = kH / 32;
    for (int t = 0; t < nt; ++t) {
        const int buf = t & 1;
        if (t + 1 < nt) {
            const int kn = (t + 1) * 32;
            gload_lds16(aSrc0 + kn, &As[buf ^ 1][c0i * 512]);
            gload_lds16(aSrc1 + kn, &As[buf ^ 1][c1i * 512]);
            gload_lds16(bSrc0 + kn, &Bs[buf ^ 1][c0i * 512]);
            gload_lds16(bSrc1 + kn, &Bs[buf ^ 1][c1i * 512]);
        }
        const char* Ab = (const char*)As[buf];
        const char* Bb = (const char*)Bs[buf];
        short8 af[4], bfr[4];
        #pragma unroll
        for (int mm = 0; mm < 4; ++mm)
            af[mm] = *(const short8*)(Ab + (wrow + mm * 16) * 64 + fragOff);
        #pragma unroll
        for (int nn = 0; nn < 4; ++nn)
            bfr[nn] = *(const short8*)(Bb + (wcol + nn * 16) * 64 + fragOff);
        #pragma unroll
        for (int mm = 0; mm < 4; ++mm)
            #pragma unroll
            for (int nn = 0; nn < 4; ++nn)
                acc[mm][nn] = __builtin_amdgcn_mfma_f32_16x16x32_bf16(
                    af[mm], bfr[nn], acc[mm][nn], 0, 0, 0);
        if (t + 1 < nt) __syncthreads();
    }

    const float* be = b2 + (size_t)e * kD + n0;
    const int* tok = tokList + e * kCap;
    const float* gate = gateList + e * kCap;
    #pragma unroll
    for (int mm = 0; mm < 4; ++mm) {
        #pragma unroll
        for (int i = 0; i < 4; ++i) {
            const int r = m0 + wrow + mm * 16 + g * 4 + i;
            if (r >= count) continue;
            const int tokn = tok[r];
            const float gr = gate[r];
            float* orow = out + (size_t)tokn * kD + n0;
            #pragma unroll
            for (int nn = 0; nn < 4; ++nn) {
                const int c = wcol + nn * 16 + l15;
                atomicAdd(orow + c, (acc[mm][nn][i] + be[c]) * gr);   // <=2 addends: deterministic
            }
        }
    }
}

// ---------------- launch ----------------
extern "C" void kernel_launch(void* const* d_in, const int* in_sizes, int n_in,
                              void* d_out, int out_size, void* d_ws, size_t ws_size,
                              hipStream_t stream)
{
    const float* x         = (const float*)d_in[0];
    const float* noise_raw = (const float*)d_in[1];
    const float* Wr        = (const float*)d_in[2];
    const float* br        = (const float*)d_in[3];
    const float* Wn        = (const float*)d_in[4];
    const float* bn        = (const float*)d_in[5];
    const float* W1        = (const float*)d_in[6];
    const float* b1        = (const float*)d_in[7];
    const float* W2        = (const float*)d_in[8];
    const float* b2        = (const float*)d_in[9];
    float* out = (float*)d_out;

    char* ws = (char*)d_ws;
    size_t off = 0;
    auto alloc = [&](size_t bytes) -> void* {
        void* p = ws + off;
        off = (off + bytes + 255) & ~(size_t)255;
        return p;
    };
    int2*   topIdx   = (int2*)  alloc((size_t)kN * sizeof(int2));
    float2* topProb  = (float2*)alloc((size_t)kN * sizeof(float2));
    int*    tokList  = (int*)   alloc((size_t)kE * kCap * sizeof(int));
    float*  gateList = (float*) alloc((size_t)kE * kCap * sizeof(float));
    int*    cnt      = (int*)   alloc((size_t)kE * sizeof(int));

    unsigned short* xb  = (unsigned short*)alloc((size_t)kN * kD * 2);        // 32 MB
    unsigned short* W1t = (unsigned short*)alloc((size_t)kE * kD * kH * 2);   // 64 MB
    unsigned short* W2t = (unsigned short*)alloc((size_t)kE * kH * kD * 2);   // 64 MB

    const size_t HB = (size_t)kCap * kH * 2;   // 32 MB / expert
    size_t rem = (ws_size > off) ? ws_size - off : 0;
    int G = (int)(rem / HB);
    if (G > 4) G = 4;
    if (G < 1) G = 1;
    unsigned short* Hbuf = (unsigned short*)(ws + off);

    moe_zero_out<<<(kN * kD / 4 + 255) / 256, 256, 0, stream>>>((float4*)out, kN * kD / 4);
    moe_router<<<kN / 4, 256, 0, stream>>>(x, noise_raw, Wr, br, Wn, bn, topIdx, topProb);
    moe_dispatch<<<kE, 64, 0, stream>>>(topIdx, topProb, tokList, gateList, cnt);
    moe_cvt_x<<<kN * kD / 8 / 256, 256, 0, stream>>>((const float4*)x, (short8*)xb, kN * kD / 8);
    // W1 [E][D][H] -> W1t [E][H][D]
    moe_tcvt<<<dim3(kH / 64, kD / 64, kE), 256, 0, stream>>>(W1, W1t, kD, kH);
    // W2 [E][H][D] -> W2t [E][D][H]
    moe_tcvt<<<dim3(kD / 64, kH / 64, kE), 256, 0, stream>>>(W2, W2t, kH, kD);

    for (int e0 = 0; e0 < kE; e0 += G) {
        const int gz = (kE - e0 < G) ? (kE - e0) : G;
        moe_ffn1_g<<<dim3(kH / 128, kCap / 128, gz), 256, 0, stream>>>(
            xb, W1t, b1, tokList, cnt, Hbuf, e0);
        moe_ffn2_g<<<dim3(kD / 128, kCap / 128, gz), 256, 0, stream>>>(
            Hbuf, W2t, b2, tokList, gateList, cnt, out, e0);
    }
}